// Round 1
// baseline (75.181 us; speedup 1.0000x reference)
//
#include <hip/hip_runtime.h>

#define NEG_INF (-__builtin_inff())
#define MCAP 64

// -------- zero workspace accumulators --------
__global__ __launch_bounds__(256) void zero_kernel(float* __restrict__ p, long long words) {
  long long idx = (long long)blockIdx.x * 256 + threadIdx.x;
  if (idx < words) p[idx] = 0.0f;
}

// -------- compact top-S candidate list: list = {i : S[i] >= tau} --------
__global__ __launch_bounds__(256) void compact_kernel(const float* __restrict__ S, float tau,
                                                      int* __restrict__ list, int* __restrict__ Lc, int N) {
  int i = blockIdx.x * 256 + threadIdx.x;
  if (i < N && S[i] >= tau) {
    int p = atomicAdd(Lc, 1);
    list[p] = i;
  }
}

// -------- leader[i] = argmax over topSet∩nbr(i) ∪ {i}; exact when any topSet nbr exists --------
__global__ __launch_bounds__(256) void assign_kernel(const float* __restrict__ J, const float* __restrict__ S,
                                                     const int* __restrict__ list, const int* __restrict__ Lc,
                                                     float tau, int* __restrict__ leader,
                                                     int* __restrict__ unres, int* __restrict__ Uc, int N) {
  int i = blockIdx.x * 256 + threadIdx.x;
  if (i >= N) return;
  const int T = *Lc;
  float si = S[i];
  float best = si;     // self is always a candidate (adj includes eye)
  int bidx = i;
  bool found = (si >= tau);   // self in topSet -> resolved
  for (int t = 0; t < T; ++t) {
    int cand = list[t];
    // J symmetric: J[i][cand] == J[cand][i]; read row-major for coalescing over i
    float v = J[(size_t)cand * N + i];
    if (v > 0.5f) {
      found = true;
      float c = S[cand];
      // max value, ties -> smallest original index (jnp.argmax first-occurrence)
      if (c > best || (c == best && cand < bidx)) { best = c; bidx = cand; }
    }
  }
  leader[i] = bidx;
  if (!found) {
    int p = atomicAdd(Uc, 1);
    unres[p] = i;
  }
}

// -------- exact full-row argmax for unresolved rows (expected: none) --------
__global__ __launch_bounds__(256) void fallback_kernel(const float* __restrict__ J, const float* __restrict__ S,
                                                       const int* __restrict__ unres, const int* __restrict__ Uc,
                                                       int* __restrict__ leader, int N) {
  __shared__ float sv_[4];
  __shared__ int si_[4];
  const int U = *Uc;
  for (int u = blockIdx.x; u < U; u += gridDim.x) {
    int i = unres[u];
    const float* row = J + (size_t)i * N;
    float best = NEG_INF;
    int bidx = 0x7fffffff;
    for (int j = threadIdx.x; j < N; j += 256) {
      float c = (row[j] > 0.5f || j == i) ? S[j] : NEG_INF;
      if (c > best) { best = c; bidx = j; }   // within-thread j increases: strict > keeps first
    }
    for (int off = 32; off >= 1; off >>= 1) {
      float ov = __shfl_down(best, off, 64);
      int oi = __shfl_down(bidx, off, 64);
      if (ov > best || (ov == best && oi < bidx)) { best = ov; bidx = oi; }
    }
    int wv = threadIdx.x >> 6;
    if ((threadIdx.x & 63) == 0) { sv_[wv] = best; si_[wv] = bidx; }
    __syncthreads();
    if (threadIdx.x == 0) {
      for (int w = 1; w < 4; ++w) {
        float ov = sv_[w]; int oi = si_[w];
        if (ov > best || (ov == best && oi < bidx)) { best = ov; bidx = oi; }
      }
      leader[i] = bidx;
    }
    __syncthreads();
  }
}

// -------- counts via wave-aggregated histogram (avoid 4096-way same-address atomics) --------
__global__ __launch_bounds__(256) void count_kernel(const int* __restrict__ leader,
                                                    int* __restrict__ counts, int N) {
  int i = blockIdx.x * 256 + threadIdx.x;
  bool active = (i < N);
  int L = active ? leader[i] : -1;
  int lane = threadIdx.x & 63;
  unsigned long long remaining = __ballot(active);
  while (remaining) {
    int src = (int)__ffsll(remaining) - 1;
    int Lf = __shfl(L, src, 64);
    unsigned long long same = __ballot(active && (L == Lf));
    if (lane == src) atomicAdd(&counts[Lf], (int)__popcll(same));
    remaining &= ~same;
  }
}

// -------- compact leader-id map: m in [0,M) for ids with count>0 --------
__global__ __launch_bounds__(256) void buildmap_kernel(const int* __restrict__ counts,
                                                       int* __restrict__ map, int* __restrict__ rmap,
                                                       int* __restrict__ Mc, int N) {
  int i = blockIdx.x * 256 + threadIdx.x;
  if (i >= N) return;
  if (counts[i] > 0) {
    int m = atomicAdd(Mc, 1);
    map[i] = m;
    if (m < N) rmap[m] = i;
  } else {
    map[i] = -1;
  }
}

// -------- segment sums of C and D via per-block LDS slab (contention-free) --------
__global__ __launch_bounds__(256) void scatter_kernel(const float* __restrict__ C, const float* __restrict__ D,
                                                      const int* __restrict__ leader, const int* __restrict__ map,
                                                      const int* __restrict__ rmap, const int* __restrict__ Mc,
                                                      float* __restrict__ sumC, float* __restrict__ sumD,
                                                      int N, int K) {
  extern __shared__ float slab[];        // [2][MCAP][K]
  const int M = *Mc;
  const int t = threadIdx.x;
  const int rowsPerBlock = (N + gridDim.x - 1) / gridDim.x;
  const int r0 = blockIdx.x * rowsPerBlock;
  const int r1 = min(N, r0 + rowsPerBlock);
  const int wave = t >> 6, lane = t & 63, nwaves = blockDim.x >> 6;

  if (M <= MCAP) {
    float* slabC = slab;
    float* slabD = slab + MCAP * K;
    for (int idx = t; idx < 2 * MCAP * K; idx += blockDim.x) slab[idx] = 0.0f;
    __syncthreads();
    for (int i = r0 + wave; i < r1; i += nwaves) {
      int m = map[leader[i]];
      const float* cRow = C + (size_t)i * K;
      const float* dRow = D + (size_t)i * K;
      for (int k = lane; k < K; k += 64) {     // lanes -> consecutive k: no LDS bank conflict
        atomicAdd(&slabC[m * K + k], cRow[k]);
        atomicAdd(&slabD[m * K + k], dRow[k]);
      }
    }
    __syncthreads();
    for (int idx = t; idx < M * K; idx += blockDim.x) {
      int m = idx / K, k = idx - m * K;
      int L = rmap[m];
      atomicAdd(&sumC[(size_t)L * K + k], slabC[m * K + k]);
      atomicAdd(&sumD[(size_t)L * K + k], slabD[m * K + k]);
    }
  } else {
    // many small cliques -> low contention, direct atomics are fine
    for (int i = r0 + wave; i < r1; i += nwaves) {
      int L = leader[i];
      const float* cRow = C + (size_t)i * K;
      const float* dRow = D + (size_t)i * K;
      for (int k = lane; k < K; k += 64) {
        atomicAdd(&sumC[(size_t)L * K + k], cRow[k]);
        atomicAdd(&sumD[(size_t)L * K + k], dRow[k]);
      }
    }
  }
}

// -------- out[i][k] = sum[leader[i]][k] / counts[leader[i]] --------
__global__ __launch_bounds__(256) void finalize_kernel(const float* __restrict__ sumC, const float* __restrict__ sumD,
                                                       const int* __restrict__ leader, const int* __restrict__ counts,
                                                       float* __restrict__ out, int N, int K) {
  const int NK = N * K;
  int idx = blockIdx.x * 256 + threadIdx.x;
  if (idx >= 2 * NK) return;
  int rem = (idx < NK) ? idx : idx - NK;
  int i = rem / K;
  int k = rem - i * K;
  int L = leader[i];
  int c = counts[L];
  float inv = 1.0f / (float)(c > 0 ? c : 1);
  const float* src = (idx < NK) ? sumC : sumD;
  out[idx] = src[(size_t)L * K + k] * inv;
}

extern "C" void kernel_launch(void* const* d_in, const int* in_sizes, int n_in,
                              void* d_out, int out_size, void* d_ws, size_t ws_size,
                              hipStream_t stream) {
  (void)n_in; (void)out_size; (void)ws_size;
  const float* S = (const float*)d_in[0];
  const float* J = (const float*)d_in[1];
  const float* C = (const float*)d_in[2];
  const float* D = (const float*)d_in[3];
  float* out = (float*)d_out;
  const int N = in_sizes[0];
  const int K = in_sizes[2] / N;
  const int NK = N * K;

  // workspace layout (zeroed region first): sumC | sumD | counts | Mc Lc Uc | leader | map | rmap | list | unres
  float* sumC   = (float*)d_ws;
  float* sumD   = sumC + NK;
  int*   counts = (int*)(sumD + NK);
  int*   Mc     = counts + N;
  int*   Lc     = Mc + 1;
  int*   Uc     = Lc + 1;
  int*   leader = Uc + 1;
  int*   map    = leader + N;
  int*   rmap   = map + N;
  int*   list   = rmap + N;
  int*   unres  = list + N;

  const long long zwords = 2LL * NK + N + 3;
  zero_kernel<<<(int)((zwords + 255) / 256), 256, 0, stream>>>((float*)d_ws, zwords);

  const float tau = 1.0f - 64.0f / (float)N;   // any tau is correct; this targets ~64 candidates
  compact_kernel<<<(N + 255) / 256, 256, 0, stream>>>(S, tau, list, Lc, N);
  assign_kernel<<<(N + 255) / 256, 256, 0, stream>>>(J, S, list, Lc, tau, leader, unres, Uc, N);
  fallback_kernel<<<256, 256, 0, stream>>>(J, S, unres, Uc, leader, N);
  count_kernel<<<(N + 255) / 256, 256, 0, stream>>>(leader, counts, N);
  buildmap_kernel<<<(N + 255) / 256, 256, 0, stream>>>(counts, map, rmap, Mc, N);
  size_t shmem = (size_t)2 * MCAP * K * sizeof(float);
  scatter_kernel<<<64, 256, shmem, stream>>>(C, D, leader, map, rmap, Mc, sumC, sumD, N, K);
  finalize_kernel<<<(2 * NK + 255) / 256, 256, 0, stream>>>(sumC, sumD, leader, counts, out, N, K);
}

// Round 2
// 39.656 us; speedup vs baseline: 1.8958x; 1.8958x over previous
//
#include <hip/hip_runtime.h>

#define LCAP  128          // candidate-list / slab capacity (slots)
#define KF    80           // compiled K (harness: K=80)
#define NPART 8            // partitioned partial sums: contention cap = 256/NPART = 32

// ---------------- zero workspace (float4) ----------------
__global__ __launch_bounds__(256) void zeroK(float4* __restrict__ p, int n4) {
  int idx = blockIdx.x * 256 + threadIdx.x;
  if (idx < n4) p[idx] = make_float4(0.f, 0.f, 0.f, 0.f);
}

// ---------------- fused: list build + assign + counts + scatter ----------------
__global__ __launch_bounds__(256) void mainK(const float* __restrict__ S, const float* __restrict__ J,
                                             const float* __restrict__ C, const float* __restrict__ D,
                                             float tau,
                                             float* __restrict__ slotPartC, float* __restrict__ slotPartD,
                                             int* __restrict__ counts,
                                             float* __restrict__ idSumC, float* __restrict__ idSumD,
                                             int* __restrict__ leader, int* __restrict__ lslot,
                                             int N, int K) {
  __shared__ int   listIdx[LCAP];
  __shared__ float listVal[LCAP];
  __shared__ float slabC[LCAP * KF];
  __shared__ float slabD[LCAP * KF];
  __shared__ int   slotCnt[LCAP];
  __shared__ unsigned long long rowKey[32];
  __shared__ int   rowSlot[32];
  __shared__ int   cnts[256];
  __shared__ int   sT;
  __shared__ int   sOvf;
  __shared__ int   nUnres;
  __shared__ int   unresList[32];
  __shared__ unsigned long long bruteKey;

  const int tid = threadIdx.x;
  const int b   = blockIdx.x;

  // ---- A: rebuild the (block-invariant) candidate list {j : S[j] >= tau}, index-ascending ----
  const int per = (N + 255) / 256;
  const int j0 = tid * per, j1 = min(N, j0 + per);
  int cl = 0;
  for (int j = j0; j < j1; ++j) cl += (S[j] >= tau);
  cnts[tid] = cl;
  if (tid == 0) { nUnres = 0; }
  __syncthreads();
  if (tid < 64) {                       // wave-0 exclusive prefix over 256 counts
    const int base = tid * 4;
    int a0 = cnts[base], a1 = cnts[base + 1], a2 = cnts[base + 2], a3 = cnts[base + 3];
    int s = a0 + a1 + a2 + a3;
    int inc = s;
    for (int off = 1; off < 64; off <<= 1) {
      int o = __shfl_up(inc, off, 64);
      if (tid >= off) inc += o;
    }
    int exc = inc - s;
    cnts[base] = exc; cnts[base + 1] = exc + a0;
    cnts[base + 2] = exc + a0 + a1; cnts[base + 3] = exc + a0 + a1 + a2;
    if (tid == 63) { sT = inc; sOvf = (inc > LCAP); }
  }
  __syncthreads();
  const int T   = sT;
  const int ovf = sOvf | (K != KF);     // unconditional-correctness escape hatch
  if (!ovf) {
    int pos = cnts[tid];
    for (int j = j0; j < j1; ++j) {
      float v = S[j];
      if (v >= tau) { listIdx[pos] = j; listVal[pos] = v; ++pos; }
    }
  }
  if (tid < LCAP) slotCnt[tid] = 0;
  if (tid < 32) { rowKey[tid] = 0ull; rowSlot[tid] = -1; }
  __syncthreads();

  // ---- B: leader assignment, 8 threads per row over list slots ----
  const int c8 = tid >> 5;              // 0..7 candidate group
  const int r  = tid & 31;              // 0..31 row within block
  const int i  = b * 32 + r;
  if (!ovf && i < N) {
    unsigned long long lkey = 0ull;
    #pragma unroll 4
    for (int t = c8; t < T; t += 8) {
      int cand = listIdx[t];
      float v = J[(size_t)cand * N + i];      // symmetric J: column read, coalesced over r
      if (v > 0.5f) {
        unsigned mb = __float_as_uint(listVal[t]);
        mb = (mb >> 31) ? ~mb : (mb | 0x80000000u);   // order-preserving float->uint
        unsigned long long key = ((unsigned long long)mb << 32) | (unsigned)(0xFFFFFFFFu - t);
        if (key > lkey) lkey = key;           // slots index-ascending -> min slot == min index
      }
    }
    if (lkey) atomicMax(&rowKey[r], lkey);
  }
  __syncthreads();
  if (c8 == 0 && i < N) {
    unsigned long long k = rowKey[r];
    if (!ovf && k != 0ull) {
      int slot = (int)(0xFFFFFFFFu - (unsigned)(k & 0xFFFFFFFFu));
      rowSlot[r] = slot;
      leader[i]  = listIdx[slot];
      lslot[i]   = slot;
      atomicAdd(&slotCnt[slot], 1);
    } else {                                  // no top-set neighbor (or overflow): exact path
      int u = atomicAdd(&nUnres, 1);
      unresList[u] = r;
      lslot[i] = -1;
    }
  }
  __syncthreads();

  // ---- B': exact full-row argmax for unresolved rows (expected: none) ----
  const int nu = nUnres;
  for (int u = 0; u < nu; ++u) {
    const int rr = unresList[u];
    const int ii = b * 32 + rr;
    if (tid == 0) bruteKey = 0ull;
    __syncthreads();
    unsigned long long bk = 0ull;
    for (int j = tid; j < N; j += 256) {
      float v = J[(size_t)j * N + ii];
      if (v > 0.5f || j == ii) {
        unsigned mb = __float_as_uint(S[j]);
        mb = (mb >> 31) ? ~mb : (mb | 0x80000000u);
        unsigned long long key = ((unsigned long long)mb << 32) | (unsigned)(0xFFFFFFFFu - j);
        if (key > bk) bk = key;
      }
    }
    if (bk) atomicMax(&bruteKey, bk);
    __syncthreads();
    if (tid == 0) {
      int js = (int)(0xFFFFFFFFu - (unsigned)(bruteKey & 0xFFFFFFFFu));
      leader[ii] = js;
      atomicAdd(&counts[js], 1);              // id-keyed; provably disjoint from list ids
    }
    __syncthreads();
  }

  // ---- C: segment-sum scatter via LDS slab ----
  if (!ovf) {
    for (int idx = tid; idx < LCAP * KF; idx += 256) { slabC[idx] = 0.f; slabD[idx] = 0.f; }
  }
  __syncthreads();
  const int wv = tid >> 6, lane = tid & 63;
  for (int rr = wv; rr < 32; rr += 4) {
    const int ii = b * 32 + rr;
    if (ii >= N) continue;
    const int m = rowSlot[rr];
    const float* cR = C + (size_t)ii * K;
    const float* dR = D + (size_t)ii * K;
    if (m >= 0) {
      for (int k = lane; k < K; k += 64) {    // lanes -> consecutive k: conflict-free LDS
        atomicAdd(&slabC[m * KF + k], cR[k]);
        atomicAdd(&slabD[m * KF + k], dR[k]);
      }
    } else {
      const int L = leader[ii];
      for (int k = lane; k < K; k += 64) {
        atomicAdd(&idSumC[(size_t)L * K + k], cR[k]);
        atomicAdd(&idSumD[(size_t)L * K + k], dR[k]);
      }
    }
  }
  __syncthreads();

  // ---- D: flush counts + touched slot slabs into partitioned partials ----
  if (!ovf) {
    if (tid < T && slotCnt[tid] > 0)
      atomicAdd(&counts[listIdx[tid]], slotCnt[tid]);
    const int p = b & (NPART - 1);
    for (int t = 0; t < T; ++t) {             // block-uniform loop; skip untouched slots
      if (slotCnt[t] == 0) continue;
      float* dstC = slotPartC + ((size_t)p * LCAP + t) * KF;
      float* dstD = slotPartD + ((size_t)p * LCAP + t) * KF;
      if (tid < KF)                         atomicAdd(&dstC[tid],        slabC[t * KF + tid]);
      else if (tid >= 128 && tid < 128 + KF) atomicAdd(&dstD[tid - 128], slabD[t * KF + (tid - 128)]);
    }
  }
}

// ---------------- finalize: out[i,k] = sum[leader]/count (float4) ----------------
__global__ __launch_bounds__(256) void finalizeK(const float* __restrict__ slotPartC,
                                                 const float* __restrict__ slotPartD,
                                                 const int* __restrict__ counts,
                                                 const float* __restrict__ idSumC,
                                                 const float* __restrict__ idSumD,
                                                 const int* __restrict__ leader,
                                                 const int* __restrict__ lslot,
                                                 float* __restrict__ out, int N, int K) {
  const int NK4 = N * K / 4;
  int idx = blockIdx.x * 256 + threadIdx.x;
  if (idx >= 2 * NK4) return;
  const bool isD = (idx >= NK4);
  const int rem = isD ? idx - NK4 : idx;
  const int kq = K / 4;
  const int i  = rem / kq;
  const int k0 = (rem - i * kq) * 4;
  const int L  = leader[i];
  const int c  = counts[L];
  const float inv = 1.0f / (float)(c > 0 ? c : 1);
  const int slot = lslot[i];
  float4 acc;
  if (slot >= 0) {
    acc = make_float4(0.f, 0.f, 0.f, 0.f);
    const float* base = (isD ? slotPartD : slotPartC) + (size_t)slot * KF + k0;
    #pragma unroll
    for (int p = 0; p < NPART; ++p) {
      float4 v = *(const float4*)(base + (size_t)p * LCAP * KF);
      acc.x += v.x; acc.y += v.y; acc.z += v.z; acc.w += v.w;
    }
  } else {
    acc = *(const float4*)((isD ? idSumD : idSumC) + (size_t)L * K + k0);
  }
  acc.x *= inv; acc.y *= inv; acc.z *= inv; acc.w *= inv;
  ((float4*)out)[idx] = acc;
}

extern "C" void kernel_launch(void* const* d_in, const int* in_sizes, int n_in,
                              void* d_out, int out_size, void* d_ws, size_t ws_size,
                              hipStream_t stream) {
  (void)n_in; (void)out_size; (void)ws_size;
  const float* S = (const float*)d_in[0];
  const float* J = (const float*)d_in[1];
  const float* C = (const float*)d_in[2];
  const float* D = (const float*)d_in[3];
  float* out = (float*)d_out;
  const int N  = in_sizes[0];
  const int K  = in_sizes[2] / N;
  const int NK = N * K;
  const int PSZ = NPART * LCAP * KF;

  // ws layout: slotPartC | slotPartD | counts | idSumC | idSumD | leader | lslot
  float* slotPartC = (float*)d_ws;
  float* slotPartD = slotPartC + PSZ;
  int*   counts    = (int*)(slotPartD + PSZ);
  float* idSumC    = (float*)(counts + N);
  float* idSumD    = idSumC + NK;
  int*   leader    = (int*)(idSumD + NK);
  int*   lslot     = leader + N;

  const long long zwords = 2LL * PSZ + N + 2LL * NK;   // all components %4 == 0
  const int n4 = (int)(zwords / 4);
  zeroK<<<(n4 + 255) / 256, 256, 0, stream>>>((float4*)d_ws, n4);

  const float tau = 1.0f - 48.0f / (float)N;   // targets E[T]=48 candidates; any tau is correct
  const int nblk = (N + 31) / 32;
  mainK<<<nblk, 256, 0, stream>>>(S, J, C, D, tau, slotPartC, slotPartD, counts,
                                  idSumC, idSumD, leader, lslot, N, K);
  finalizeK<<<(2 * (NK / 4) + 255) / 256, 256, 0, stream>>>(slotPartC, slotPartD, counts,
                                                            idSumC, idSumD, leader, lslot,
                                                            out, N, K);
}